// Round 2
// baseline (669.831 us; speedup 1.0000x reference)
//
#include <hip/hip_runtime.h>
#include <math.h>

#define HH 96
#define WW 96
#define PP 9216   // H*W
#define CCH 256
#define BB 4
#define CH 32     // channels per head

// ---------------------------------------------------------------------------
// GEMM A: NCHW input -> channel-last output. Fused Q/K/V projections.
// Y[b][p][o] = sum_c W[o][c] * X[b][c][p]
// 128o x 128p tile, 256 threads, 8x8 per thread, c-chunks of 32.
// ---------------------------------------------------------------------------
__global__ __launch_bounds__(256)
void gemm_qkv(const float* __restrict__ qin, const float* __restrict__ kin,
              const float* __restrict__ vin, const float* __restrict__ Wm,
              float* __restrict__ Yall) {
  __shared__ float Xt[32][128];   // [c][p]
  __shared__ float Wt[32][136];   // [c][o], padded
  const int t = threadIdx.x;
  const int pblk = blockIdx.x * 128;
  const int oblk = blockIdx.y * 128;
  const int b = blockIdx.z & 3;
  const int which = blockIdx.z >> 2;
  const float* X = (which == 0) ? qin : (which == 1) ? kin : vin;
  const float* Xb = X + (size_t)b * CCH * PP;
  float* Y = Yall + (size_t)which * ((size_t)BB * PP * CCH);

  float acc[8][8];
#pragma unroll
  for (int i = 0; i < 8; i++)
#pragma unroll
    for (int j = 0; j < 8; j++) acc[i][j] = 0.f;
  const int ogrp = t & 15;   // o fastest across lanes -> channel-last stores coalesce
  const int pgrp = t >> 4;

  for (int c0 = 0; c0 < CCH; c0 += 32) {
#pragma unroll
    for (int k = 0; k < 4; k++) {           // stage X tile (coalesced along p)
      int i4 = t + k * 256;
      int c = i4 >> 5;
      int p4 = i4 & 31;
      float4 v = *(const float4*)(Xb + (size_t)(c0 + c) * PP + pblk + p4 * 4);
      *(float4*)(&Xt[c][p4 * 4]) = v;
    }
#pragma unroll
    for (int k = 0; k < 4; k++) {           // stage W tile transposed
      int i4 = t + k * 256;
      int oo = i4 >> 3;
      int c4 = i4 & 7;
      float4 v = *(const float4*)(Wm + (size_t)(oblk + oo) * CCH + c0 + c4 * 4);
      Wt[c4 * 4 + 0][oo] = v.x;
      Wt[c4 * 4 + 1][oo] = v.y;
      Wt[c4 * 4 + 2][oo] = v.z;
      Wt[c4 * 4 + 3][oo] = v.w;
    }
    __syncthreads();
#pragma unroll
    for (int c = 0; c < 32; c++) {
      float4 x0 = *(const float4*)(&Xt[c][pgrp * 8]);
      float4 x1 = *(const float4*)(&Xt[c][pgrp * 8 + 4]);
      float4 w0 = *(const float4*)(&Wt[c][ogrp * 8]);
      float4 w1 = *(const float4*)(&Wt[c][ogrp * 8 + 4]);
      float xs[8] = {x0.x, x0.y, x0.z, x0.w, x1.x, x1.y, x1.z, x1.w};
      float ws[8] = {w0.x, w0.y, w0.z, w0.w, w1.x, w1.y, w1.z, w1.w};
#pragma unroll
      for (int i = 0; i < 8; i++)
#pragma unroll
        for (int j = 0; j < 8; j++) acc[i][j] = fmaf(ws[i], xs[j], acc[i][j]);
    }
    __syncthreads();
  }
  // channel-last epilogue: Y[(b*PP+p)*256 + o]
  const int o = oblk + ogrp * 8;
#pragma unroll
  for (int j = 0; j < 8; j++) {
    size_t row = ((size_t)b * PP + pblk + pgrp * 8 + j) * CCH + o;
    float4 v0 = {acc[0][j], acc[1][j], acc[2][j], acc[3][j]};
    float4 v1 = {acc[4][j], acc[5][j], acc[6][j], acc[7][j]};
    *(float4*)(Y + row) = v0;
    *(float4*)(Y + row + 4) = v1;
  }
}

// ---------------------------------------------------------------------------
// GEMM B: channel-last input -> NCHW output, + bias. (out projection)
// out[b][o][p] = sum_c W[o][c] * Ot[b][p][c] + bo[o]
// ---------------------------------------------------------------------------
__global__ __launch_bounds__(256)
void gemm_out(const float* __restrict__ Ot, const float* __restrict__ Wm,
              const float* __restrict__ bias, float* __restrict__ Y) {
  __shared__ float Xt[32][132];   // [c][p], stride 132 (16B-aligned rows), XOR-swizzled p
  __shared__ float Wt[32][136];
  const int t = threadIdx.x;
  const int pblk = blockIdx.x * 128;
  const int oblk = blockIdx.y * 128;
  const int b = blockIdx.z;

  float acc[8][8];
#pragma unroll
  for (int i = 0; i < 8; i++)
#pragma unroll
    for (int j = 0; j < 8; j++) acc[i][j] = 0.f;
  const int pgrp = t & 15;   // p fastest across lanes -> NCHW stores coalesce
  const int ogrp = t >> 4;

  for (int c0 = 0; c0 < CCH; c0 += 32) {
    // stage X tile from channel-last: transpose into Xt[c][p] with swizzle
#pragma unroll
    for (int k = 0; k < 4; k++) {
      int i4 = t + k * 256;
      int pl = i4 >> 3;               // 0..127
      int c4 = i4 & 7;                // 8 float4 across 32 c
      float4 v = *(const float4*)(Ot + ((size_t)b * PP + pblk + pl) * CCH + c0 + c4 * 4);
      int swz = (c4 & 3) << 3;        // ((c>>2)&3)<<3 with c = c4*4+r
      Xt[c4 * 4 + 0][pl ^ swz] = v.x;
      Xt[c4 * 4 + 1][pl ^ swz] = v.y;
      Xt[c4 * 4 + 2][pl ^ swz] = v.z;
      Xt[c4 * 4 + 3][pl ^ swz] = v.w;
    }
#pragma unroll
    for (int k = 0; k < 4; k++) {
      int i4 = t + k * 256;
      int oo = i4 >> 3;
      int c4 = i4 & 7;
      float4 v = *(const float4*)(Wm + (size_t)(oblk + oo) * CCH + c0 + c4 * 4);
      Wt[c4 * 4 + 0][oo] = v.x;
      Wt[c4 * 4 + 1][oo] = v.y;
      Wt[c4 * 4 + 2][oo] = v.z;
      Wt[c4 * 4 + 3][oo] = v.w;
    }
    __syncthreads();
#pragma unroll
    for (int c = 0; c < 32; c++) {
      int pp_ = (pgrp * 8) ^ (((c >> 2) & 3) << 3);
      float4 x0 = *(const float4*)(&Xt[c][pp_]);
      float4 x1 = *(const float4*)(&Xt[c][pp_ + 4]);
      float4 w0 = *(const float4*)(&Wt[c][ogrp * 8]);
      float4 w1 = *(const float4*)(&Wt[c][ogrp * 8 + 4]);
      float xs[8] = {x0.x, x0.y, x0.z, x0.w, x1.x, x1.y, x1.z, x1.w};
      float ws[8] = {w0.x, w0.y, w0.z, w0.w, w1.x, w1.y, w1.z, w1.w};
#pragma unroll
      for (int i = 0; i < 8; i++)
#pragma unroll
        for (int j = 0; j < 8; j++) acc[i][j] = fmaf(ws[i], xs[j], acc[i][j]);
    }
    __syncthreads();
  }
#pragma unroll
  for (int i = 0; i < 8; i++) {
    int o = oblk + ogrp * 8 + i;
    float bv = bias[o];
    float* Yp = Y + ((size_t)b * CCH + o) * PP + pblk + pgrp * 8;
    float4 v0 = {acc[i][0] + bv, acc[i][1] + bv, acc[i][2] + bv, acc[i][3] + bv};
    float4 v1 = {acc[i][4] + bv, acc[i][5] + bv, acc[i][6] + bv, acc[i][7] + bv};
    *(float4*)(Yp) = v0;
    *(float4*)(Yp + 4) = v1;
  }
}

// ---------------------------------------------------------------------------
// Attention core, channel-last. Q/K/V are [b][p][256]; head h owns channels
// h*32..h*32+31 (contiguous 128B). One thread per (pixel, head).
// Writes O in-place into Qt (each thread only touches its own 128B slot).
// ---------------------------------------------------------------------------
__global__ __launch_bounds__(256)
void attn_cl(const float* __restrict__ Kt, const float* __restrict__ Vt,
             float* __restrict__ Qt, const float* __restrict__ pe_dw,
             const float* __restrict__ pe_pw) {
  __shared__ float coef[81];
  if (threadIdx.x < 81)
    coef[threadIdx.x] = pe_pw[threadIdx.x] * pe_dw[threadIdx.x % 9];
  __syncthreads();

  const int t = threadIdx.x;
  const int h = t & 7;
  const int pl = t >> 3;               // 0..31 -> 8x4 pixel tile
  const int x = blockIdx.x * 8 + (pl & 7);
  const int y = blockIdx.y * 4 + (pl >> 3);
  const int b = blockIdx.z;
  const int p = y * WW + x;
  const size_t nbase = (size_t)b * PP * CCH + h * CH;
  const size_t pixbase = nbase + (size_t)p * CCH;

  float4 q[8];
#pragma unroll
  for (int j = 0; j < 8; j++) q[j] = *(const float4*)(Qt + pixbase + j * 4);

  float f[9];
  int np[9];
  float msk[9];
#pragma unroll
  for (int kk = 0; kk < 9; kk++) {
    int dy = kk / 3 - 1, dx = kk % 3 - 1;
    int yy = y + dy, xx = x + dx;
    msk[kk] = (yy >= 0 && yy < HH && xx >= 0 && xx < WW) ? 1.f : 0.f;
    yy = min(max(yy, 0), HH - 1);                 // clamp: loads unconditional
    xx = min(max(xx, 0), WW - 1);
    np[kk] = yy * WW + xx;
    const float* kp = Kt + nbase + (size_t)np[kk] * CCH;
    float s = 0.f;
#pragma unroll
    for (int j = 0; j < 8; j++) {
      float4 kv = *(const float4*)(kp + j * 4);
      s = fmaf(q[j].x, kv.x, s);
      s = fmaf(q[j].y, kv.y, s);
      s = fmaf(q[j].z, kv.z, s);
      s = fmaf(q[j].w, kv.w, s);
    }
    f[kk] = s * msk[kk];
  }

  // PE (dw*pw folded) + softmax over 9
  float g[9], m = -1e30f;
#pragma unroll
  for (int k2 = 0; k2 < 9; k2++) {
    float s = 0.f;
#pragma unroll
    for (int kk = 0; kk < 9; kk++) s = fmaf(coef[k2 * 9 + kk], f[kk], s);
    g[k2] = s;
    m = fmaxf(m, s);
  }
  float ssum = 0.f;
#pragma unroll
  for (int k2 = 0; k2 < 9; k2++) {
    g[k2] = __expf(g[k2] - m);
    ssum += g[k2];
  }
  float inv = 1.f / ssum;
#pragma unroll
  for (int k2 = 0; k2 < 9; k2++) g[k2] *= inv * msk[k2];  // zero-padded V gather

  // O = sum_k g[k] * V[neighbor k]
  float4 o[8];
#pragma unroll
  for (int j = 0; j < 8; j++) o[j] = make_float4(0.f, 0.f, 0.f, 0.f);
#pragma unroll
  for (int kk = 0; kk < 9; kk++) {
    const float* vp = Vt + nbase + (size_t)np[kk] * CCH;
    float gv = g[kk];
#pragma unroll
    for (int j = 0; j < 8; j++) {
      float4 vv = *(const float4*)(vp + j * 4);
      o[j].x = fmaf(gv, vv.x, o[j].x);
      o[j].y = fmaf(gv, vv.y, o[j].y);
      o[j].z = fmaf(gv, vv.z, o[j].z);
      o[j].w = fmaf(gv, vv.w, o[j].w);
    }
  }
#pragma unroll
  for (int j = 0; j < 8; j++) *(float4*)(Qt + pixbase + j * 4) = o[j];
}

// ---------------------------------------------------------------------------
extern "C" void kernel_launch(void* const* d_in, const int* in_sizes, int n_in,
                              void* d_out, int out_size, void* d_ws, size_t ws_size,
                              hipStream_t stream) {
  const float* q     = (const float*)d_in[0];
  const float* k     = (const float*)d_in[1];
  const float* v     = (const float*)d_in[2];
  const float* wq    = (const float*)d_in[3];
  const float* pe_dw = (const float*)d_in[4];
  const float* pe_pw = (const float*)d_in[5];
  const float* wo    = (const float*)d_in[6];
  const float* bo    = (const float*)d_in[7];
  float* out = (float*)d_out;

  const size_t seg = (size_t)BB * PP * CCH;
  float* Qt = (float*)d_ws;       // [b][p][256] channel-last
  float* Kt = Qt + seg;
  float* Vt = Kt + seg;

  // fused Q/K/V projection: z = which*4 + b
  gemm_qkv<<<dim3(PP / 128, CCH / 128, 12), 256, 0, stream>>>(q, k, v, wq, Qt);

  attn_cl<<<dim3(WW / 8, HH / 4, BB), 256, 0, stream>>>(Kt, Vt, Qt, pe_dw, pe_pw);

  gemm_out<<<dim3(PP / 128, CCH / 128, BB), 256, 0, stream>>>(Qt, wo, bo, out);
}

// Round 3
// 320.495 us; speedup vs baseline: 2.0900x; 2.0900x over previous
//
#include <hip/hip_runtime.h>
#include <math.h>

#define HH 96
#define WW 96
#define PP 9216   // H*W
#define CCH 256
#define BB 4
#define CH 32     // channels per head

// ---------------------------------------------------------------------------
// GEMM A: NCHW input -> channel-last output. Fused Q/K/V projections.
// Y[b][p][o] = sum_c W[o][c] * X[b][c][p]
// ---------------------------------------------------------------------------
__global__ __launch_bounds__(256)
void gemm_qkv(const float* __restrict__ qin, const float* __restrict__ kin,
              const float* __restrict__ vin, const float* __restrict__ Wm,
              float* __restrict__ Yall) {
  __shared__ float Xt[32][128];   // [c][p]
  __shared__ float Wt[32][136];   // [c][o], padded
  const int t = threadIdx.x;
  const int pblk = blockIdx.x * 128;
  const int oblk = blockIdx.y * 128;
  const int b = blockIdx.z & 3;
  const int which = blockIdx.z >> 2;
  const float* X = (which == 0) ? qin : (which == 1) ? kin : vin;
  const float* Xb = X + (size_t)b * CCH * PP;
  float* Y = Yall + (size_t)which * ((size_t)BB * PP * CCH);

  float acc[8][8];
#pragma unroll
  for (int i = 0; i < 8; i++)
#pragma unroll
    for (int j = 0; j < 8; j++) acc[i][j] = 0.f;
  const int ogrp = t & 15;
  const int pgrp = t >> 4;

  for (int c0 = 0; c0 < CCH; c0 += 32) {
#pragma unroll
    for (int k = 0; k < 4; k++) {
      int i4 = t + k * 256;
      int c = i4 >> 5;
      int p4 = i4 & 31;
      float4 v = *(const float4*)(Xb + (size_t)(c0 + c) * PP + pblk + p4 * 4);
      *(float4*)(&Xt[c][p4 * 4]) = v;
    }
#pragma unroll
    for (int k = 0; k < 4; k++) {
      int i4 = t + k * 256;
      int oo = i4 >> 3;
      int c4 = i4 & 7;
      float4 v = *(const float4*)(Wm + (size_t)(oblk + oo) * CCH + c0 + c4 * 4);
      Wt[c4 * 4 + 0][oo] = v.x;
      Wt[c4 * 4 + 1][oo] = v.y;
      Wt[c4 * 4 + 2][oo] = v.z;
      Wt[c4 * 4 + 3][oo] = v.w;
    }
    __syncthreads();
#pragma unroll
    for (int c = 0; c < 32; c++) {
      float4 x0 = *(const float4*)(&Xt[c][pgrp * 8]);
      float4 x1 = *(const float4*)(&Xt[c][pgrp * 8 + 4]);
      float4 w0 = *(const float4*)(&Wt[c][ogrp * 8]);
      float4 w1 = *(const float4*)(&Wt[c][ogrp * 8 + 4]);
      float xs[8] = {x0.x, x0.y, x0.z, x0.w, x1.x, x1.y, x1.z, x1.w};
      float ws[8] = {w0.x, w0.y, w0.z, w0.w, w1.x, w1.y, w1.z, w1.w};
#pragma unroll
      for (int i = 0; i < 8; i++)
#pragma unroll
        for (int j = 0; j < 8; j++) acc[i][j] = fmaf(ws[i], xs[j], acc[i][j]);
    }
    __syncthreads();
  }
  const int o = oblk + ogrp * 8;
#pragma unroll
  for (int j = 0; j < 8; j++) {
    size_t row = ((size_t)b * PP + pblk + pgrp * 8 + j) * CCH + o;
    float4 v0 = {acc[0][j], acc[1][j], acc[2][j], acc[3][j]};
    float4 v1 = {acc[4][j], acc[5][j], acc[6][j], acc[7][j]};
    *(float4*)(Y + row) = v0;
    *(float4*)(Y + row + 4) = v1;
  }
}

// ---------------------------------------------------------------------------
// GEMM B: channel-last input -> NCHW output, + bias. (out projection)
// ---------------------------------------------------------------------------
__global__ __launch_bounds__(256)
void gemm_out(const float* __restrict__ Ot, const float* __restrict__ Wm,
              const float* __restrict__ bias, float* __restrict__ Y) {
  __shared__ float Xt[32][132];
  __shared__ float Wt[32][136];
  const int t = threadIdx.x;
  const int pblk = blockIdx.x * 128;
  const int oblk = blockIdx.y * 128;
  const int b = blockIdx.z;

  float acc[8][8];
#pragma unroll
  for (int i = 0; i < 8; i++)
#pragma unroll
    for (int j = 0; j < 8; j++) acc[i][j] = 0.f;
  const int pgrp = t & 15;
  const int ogrp = t >> 4;

  for (int c0 = 0; c0 < CCH; c0 += 32) {
#pragma unroll
    for (int k = 0; k < 4; k++) {
      int i4 = t + k * 256;
      int pl = i4 >> 3;
      int c4 = i4 & 7;
      float4 v = *(const float4*)(Ot + ((size_t)b * PP + pblk + pl) * CCH + c0 + c4 * 4);
      int swz = (c4 & 3) << 3;
      Xt[c4 * 4 + 0][pl ^ swz] = v.x;
      Xt[c4 * 4 + 1][pl ^ swz] = v.y;
      Xt[c4 * 4 + 2][pl ^ swz] = v.z;
      Xt[c4 * 4 + 3][pl ^ swz] = v.w;
    }
#pragma unroll
    for (int k = 0; k < 4; k++) {
      int i4 = t + k * 256;
      int oo = i4 >> 3;
      int c4 = i4 & 7;
      float4 v = *(const float4*)(Wm + (size_t)(oblk + oo) * CCH + c0 + c4 * 4);
      Wt[c4 * 4 + 0][oo] = v.x;
      Wt[c4 * 4 + 1][oo] = v.y;
      Wt[c4 * 4 + 2][oo] = v.z;
      Wt[c4 * 4 + 3][oo] = v.w;
    }
    __syncthreads();
#pragma unroll
    for (int c = 0; c < 32; c++) {
      int pp_ = (pgrp * 8) ^ (((c >> 2) & 3) << 3);
      float4 x0 = *(const float4*)(&Xt[c][pp_]);
      float4 x1 = *(const float4*)(&Xt[c][pp_ + 4]);
      float4 w0 = *(const float4*)(&Wt[c][ogrp * 8]);
      float4 w1 = *(const float4*)(&Wt[c][ogrp * 8 + 4]);
      float xs[8] = {x0.x, x0.y, x0.z, x0.w, x1.x, x1.y, x1.z, x1.w};
      float ws[8] = {w0.x, w0.y, w0.z, w0.w, w1.x, w1.y, w1.z, w1.w};
#pragma unroll
      for (int i = 0; i < 8; i++)
#pragma unroll
        for (int j = 0; j < 8; j++) acc[i][j] = fmaf(ws[i], xs[j], acc[i][j]);
    }
    __syncthreads();
  }
#pragma unroll
  for (int i = 0; i < 8; i++) {
    int o = oblk + ogrp * 8 + i;
    float bv = bias[o];
    float* Yp = Y + ((size_t)b * CCH + o) * PP + pblk + pgrp * 8;
    float4 v0 = {acc[i][0] + bv, acc[i][1] + bv, acc[i][2] + bv, acc[i][3] + bv};
    float4 v1 = {acc[i][4] + bv, acc[i][5] + bv, acc[i][6] + bv, acc[i][7] + bv};
    *(float4*)(Yp) = v0;
    *(float4*)(Yp + 4) = v1;
  }
}

// ---------------------------------------------------------------------------
// Attention, LDS-staged. Block = (b, h, 32x8 pixel tile). K halo then V halo
// staged through one 43.5 KB LDS buffer (zero-filled OOB => reference's
// zero-pad semantics are automatic). XOR swizzle j^=hx&7 on float4 slot kills
// the pixel-stride-128B bank conflict.
// ---------------------------------------------------------------------------
#define TX 32
#define TY 8
#define HX 34     // TX+2
#define HY 10     // TY+2
#define NHALO (HX * HY)          // 340 pixels
#define NSLOT (NHALO * 8)        // float4 slots = 2720

__global__ __launch_bounds__(256)
void attn_lds(const float* __restrict__ Kt, const float* __restrict__ Vt,
              float* __restrict__ Qt, const float* __restrict__ pe_dw,
              const float* __restrict__ pe_pw) {
  __shared__ float kv[NHALO * 32];     // 43,520 B
  __shared__ float coef[81];
  const int t = threadIdx.x;
  if (t < 81) coef[t] = pe_pw[t] * pe_dw[t % 9];

  const int x0 = blockIdx.x * TX;
  const int y0 = blockIdx.y * TY;
  const int b = blockIdx.z >> 3;
  const int h = blockIdx.z & 7;
  const size_t nbase = (size_t)b * PP * CCH + h * CH;

  const int lx = t & 31;
  const int ly = t >> 5;
  const int p = (y0 + ly) * WW + (x0 + lx);
  const size_t pixbase = nbase + (size_t)p * CCH;

  // ---- stage K halo (zero-fill OOB) ----
  for (int s = t; s < NSLOT; s += 256) {
    int pix = s >> 3, j = s & 7;
    int hy = pix / HX, hx = pix - hy * HX;
    int gx = x0 - 1 + hx, gy = y0 - 1 + hy;
    float4 v = make_float4(0.f, 0.f, 0.f, 0.f);
    if (gx >= 0 && gx < WW && gy >= 0 && gy < HH)
      v = *(const float4*)(Kt + nbase + (size_t)(gy * WW + gx) * CCH + j * 4);
    *(float4*)(&kv[pix * 32 + ((j ^ (hx & 7)) << 2)]) = v;
  }

  float4 q[8];
#pragma unroll
  for (int j = 0; j < 8; j++) q[j] = *(const float4*)(Qt + pixbase + j * 4);
  __syncthreads();

  // ---- scores ----
  float f[9];
#pragma unroll
  for (int kk = 0; kk < 9; kk++) {
    int hx = lx + kk % 3, hy = ly + kk / 3;
    const float* kp = &kv[(hy * HX + hx) * 32];
    int sw = hx & 7;
    float s = 0.f;
#pragma unroll
    for (int j = 0; j < 8; j++) {
      float4 kvv = *(const float4*)(kp + ((j ^ sw) << 2));
      s = fmaf(q[j].x, kvv.x, s);
      s = fmaf(q[j].y, kvv.y, s);
      s = fmaf(q[j].z, kvv.z, s);
      s = fmaf(q[j].w, kvv.w, s);
    }
    f[kk] = s;
  }

  // ---- PE mix + softmax over 9 ----
  float g[9], m = -1e30f;
#pragma unroll
  for (int k2 = 0; k2 < 9; k2++) {
    float s = 0.f;
#pragma unroll
    for (int kk = 0; kk < 9; kk++) s = fmaf(coef[k2 * 9 + kk], f[kk], s);
    g[k2] = s;
    m = fmaxf(m, s);
  }
  float ssum = 0.f;
#pragma unroll
  for (int k2 = 0; k2 < 9; k2++) {
    g[k2] = __expf(g[k2] - m);
    ssum += g[k2];
  }
  float inv = 1.f / ssum;
#pragma unroll
  for (int k2 = 0; k2 < 9; k2++) g[k2] *= inv;

  // ---- stage V halo into the same buffer ----
  __syncthreads();
  for (int s = t; s < NSLOT; s += 256) {
    int pix = s >> 3, j = s & 7;
    int hy = pix / HX, hx = pix - hy * HX;
    int gx = x0 - 1 + hx, gy = y0 - 1 + hy;
    float4 v = make_float4(0.f, 0.f, 0.f, 0.f);
    if (gx >= 0 && gx < WW && gy >= 0 && gy < HH)
      v = *(const float4*)(Vt + nbase + (size_t)(gy * WW + gx) * CCH + j * 4);
    *(float4*)(&kv[pix * 32 + ((j ^ (hx & 7)) << 2)]) = v;
  }
  __syncthreads();

  // ---- O = sum_k g[k] * V[neighbor k] ----
  float4 o[8];
#pragma unroll
  for (int j = 0; j < 8; j++) o[j] = make_float4(0.f, 0.f, 0.f, 0.f);
#pragma unroll
  for (int kk = 0; kk < 9; kk++) {
    int hx = lx + kk % 3, hy = ly + kk / 3;
    const float* vp = &kv[(hy * HX + hx) * 32];
    int sw = hx & 7;
    float gv = g[kk];
#pragma unroll
    for (int j = 0; j < 8; j++) {
      float4 vv = *(const float4*)(vp + ((j ^ sw) << 2));
      o[j].x = fmaf(gv, vv.x, o[j].x);
      o[j].y = fmaf(gv, vv.y, o[j].y);
      o[j].z = fmaf(gv, vv.z, o[j].z);
      o[j].w = fmaf(gv, vv.w, o[j].w);
    }
  }
#pragma unroll
  for (int j = 0; j < 8; j++) *(float4*)(Qt + pixbase + j * 4) = o[j];
}

// ---------------------------------------------------------------------------
extern "C" void kernel_launch(void* const* d_in, const int* in_sizes, int n_in,
                              void* d_out, int out_size, void* d_ws, size_t ws_size,
                              hipStream_t stream) {
  const float* q     = (const float*)d_in[0];
  const float* k     = (const float*)d_in[1];
  const float* v     = (const float*)d_in[2];
  const float* wq    = (const float*)d_in[3];
  const float* pe_dw = (const float*)d_in[4];
  const float* pe_pw = (const float*)d_in[5];
  const float* wo    = (const float*)d_in[6];
  const float* bo    = (const float*)d_in[7];
  float* out = (float*)d_out;

  const size_t seg = (size_t)BB * PP * CCH;
  float* Qt = (float*)d_ws;       // [b][p][256] channel-last
  float* Kt = Qt + seg;
  float* Vt = Kt + seg;

  gemm_qkv<<<dim3(PP / 128, CCH / 128, 12), 256, 0, stream>>>(q, k, v, wq, Qt);

  attn_lds<<<dim3(WW / TX, HH / TY, BB * 8), 256, 0, stream>>>(Kt, Vt, Qt, pe_dw, pe_pw);

  gemm_out<<<dim3(PP / 128, CCH / 128, BB), 256, 0, stream>>>(Qt, wo, bo, out);
}

// Round 4
// 149.587 us; speedup vs baseline: 4.4779x; 2.1425x over previous
//
#include <hip/hip_runtime.h>
#include <math.h>

#define HH 96
#define WW 96
#define PP 9216   // H*W
#define CCH 256
#define BB 4
#define CH 32

typedef unsigned short u16;
typedef short bf16x8 __attribute__((ext_vector_type(8)));
typedef float f32x4 __attribute__((ext_vector_type(4)));

__device__ __forceinline__ float bf2f(unsigned s) { return __uint_as_float(s << 16); }
__device__ __forceinline__ u16 f2bf(float f) {
  unsigned u = __float_as_uint(f);
  return (u16)((u + 0x7fffu + ((u >> 16) & 1u)) >> 16);
}
__device__ __forceinline__ float4 unpack8(uint2 u) {
  return make_float4(bf2f(u.x & 0xffff), bf2f(u.x >> 16),
                     bf2f(u.y & 0xffff), bf2f(u.y >> 16));
}

typedef __attribute__((address_space(1))) const unsigned int GUI;
typedef __attribute__((address_space(3))) unsigned int LUI;
__device__ __forceinline__ void gload16(const void* g, void* l) {
  __builtin_amdgcn_global_load_lds((GUI*)g, (LUI*)l, 16, 0, 0);
}

// ---------------------------------------------------------------------------
// Weight convert: wq (65536 f32) then wo -> bf16 at Wbf[0:65536], [65536:131072]
// ---------------------------------------------------------------------------
__global__ __launch_bounds__(256)
void wcvt(const float* __restrict__ wq, const float* __restrict__ wo,
          u16* __restrict__ Wbf) {
  int i = blockIdx.x * 256 + threadIdx.x;        // float4 index, 0..32767
  const float* s = (i < 16384) ? (wq + (size_t)i * 4) : (wo + (size_t)(i - 16384) * 4);
  float4 v = *(const float4*)s;
  uint2 u;
  u.x = (unsigned)f2bf(v.x) | ((unsigned)f2bf(v.y) << 16);
  u.y = (unsigned)f2bf(v.z) | ((unsigned)f2bf(v.w) << 16);
  *(uint2*)(Wbf + (size_t)i * 4) = u;
}

// ---------------------------------------------------------------------------
// Prepass: NCHW f32 -> channel-last bf16. Xcl[(which*4+b)][p][c]
// Block: 32c x 64p tile with LDS transpose.
// ---------------------------------------------------------------------------
__global__ __launch_bounds__(256)
void prepass(const float* __restrict__ q, const float* __restrict__ k,
             const float* __restrict__ v, u16* __restrict__ Xcl) {
  __shared__ float Tt[64][33];
  const int t = threadIdx.x;
  const int pblk = blockIdx.x * 64;
  const int c0 = blockIdx.y * 32;
  const int b = blockIdx.z & 3;
  const int which = blockIdx.z >> 2;
  const float* X = ((which == 0) ? q : (which == 1) ? k : v) + (size_t)b * CCH * PP;
  u16* Y = Xcl + (size_t)blockIdx.z * ((size_t)PP * CCH);

  {
    int p4 = t & 15, c = t >> 4;
#pragma unroll
    for (int i = 0; i < 2; i++) {
      int cc = c + 16 * i;
      float4 vv = *(const float4*)(X + (size_t)(c0 + cc) * PP + pblk + p4 * 4);
      Tt[p4 * 4 + 0][cc] = vv.x;
      Tt[p4 * 4 + 1][cc] = vv.y;
      Tt[p4 * 4 + 2][cc] = vv.z;
      Tt[p4 * 4 + 3][cc] = vv.w;
    }
  }
  __syncthreads();
  int p = t >> 2, cg = t & 3;
  unsigned wds[4];
#pragma unroll
  for (int j = 0; j < 4; j++) {
    u16 lo = f2bf(Tt[p][cg * 8 + 2 * j]);
    u16 hi = f2bf(Tt[p][cg * 8 + 2 * j + 1]);
    wds[j] = (unsigned)lo | ((unsigned)hi << 16);
  }
  uint4 st = {wds[0], wds[1], wds[2], wds[3]};
  *(uint4*)(Y + (size_t)(pblk + p) * CCH + c0 + cg * 8) = st;
}

// ---------------------------------------------------------------------------
// MFMA GEMM, K=256, BK=64, p-tile=64, o full 256. 4 waves: wave w owns o-range
// w*64. LDS linear rows of 128B; source-pre-swizzled granules (g ^ (row&7));
// swizzled ds_read_b128 fragment reads. 16x16x32 bf16 MFMA.
// MODE 0: D[o][p] = W*X^T, epilogue bf16 channel-last IN-PLACE into Xbuf.
//         z = which*4+b.
// MODE 1: D[p][o] = X*W^T, epilogue f32 NCHW + bias. z = b.
// ---------------------------------------------------------------------------
template <int MODE>
__global__ __launch_bounds__(256)
void gemm_mfma(u16* __restrict__ XY, const u16* __restrict__ Wbf,
               const float* __restrict__ bias, float* __restrict__ outY) {
  __shared__ u16 Wl[256 * 64];   // 32 KB
  __shared__ u16 Xl[64 * 64];    // 8 KB
  const int t = threadIdx.x;
  const int w = t >> 6, l = t & 63;
  const int lr = l & 15, lg = l >> 4;
  const int pblk = blockIdx.x * 64;
  const int z = blockIdx.z;
  u16* Xbuf = XY + (size_t)z * ((size_t)PP * CCH);

  f32x4 acc[4][4];
#pragma unroll
  for (int mi = 0; mi < 4; mi++)
#pragma unroll
    for (int ni = 0; ni < 4; ni++) acc[mi][ni] = (f32x4){0.f, 0.f, 0.f, 0.f};

  for (int kk = 0; kk < 4; kk++) {
    const int c0 = kk * 64;
    // stage W tile: 256 rows x 64c, 8 gload16 per wave
#pragma unroll
    for (int i = 0; i < 8; i++) {
      int r0 = (w * 8 + i) * 8;
      int row = r0 + (l >> 3);
      int gs = (l & 7) ^ (row & 7);
      gload16(Wbf + (size_t)row * CCH + c0 + gs * 8, (void*)&Wl[r0 * 64]);
    }
    // stage X tile: 64 rows x 64c, 2 per wave
#pragma unroll
    for (int i = 0; i < 2; i++) {
      int r0 = (w * 2 + i) * 8;
      int row = r0 + (l >> 3);
      int gs = (l & 7) ^ (row & 7);
      gload16(Xbuf + (size_t)(pblk + row) * CCH + c0 + gs * 8, (void*)&Xl[r0 * 64]);
    }
    __syncthreads();
#pragma unroll
    for (int ks = 0; ks < 2; ks++) {
      const int g = ks * 4 + lg;
      bf16x8 wf[4], xf[4];
#pragma unroll
      for (int i = 0; i < 4; i++) {
        int row = w * 64 + i * 16 + lr;
        wf[i] = *(const bf16x8*)&Wl[row * 64 + ((g ^ (row & 7)) << 3)];
      }
#pragma unroll
      for (int i = 0; i < 4; i++) {
        int row = i * 16 + lr;
        xf[i] = *(const bf16x8*)&Xl[row * 64 + ((g ^ (row & 7)) << 3)];
      }
#pragma unroll
      for (int mi = 0; mi < 4; mi++)
#pragma unroll
        for (int ni = 0; ni < 4; ni++) {
          if (MODE == 0)
            acc[mi][ni] = __builtin_amdgcn_mfma_f32_16x16x32_bf16(
                wf[mi], xf[ni], acc[mi][ni], 0, 0, 0);
          else
            acc[mi][ni] = __builtin_amdgcn_mfma_f32_16x16x32_bf16(
                xf[mi], wf[ni], acc[mi][ni], 0, 0, 0);
        }
    }
    __syncthreads();
  }

  if (MODE == 0) {
    // D[o][p]: o = w*64+mi*16+lg*4+r, p = pblk+ni*16+lr. bf16 CL in-place.
#pragma unroll
    for (int mi = 0; mi < 4; mi++)
#pragma unroll
      for (int ni = 0; ni < 4; ni++) {
        int o = w * 64 + mi * 16 + lg * 4;
        int p = pblk + ni * 16 + lr;
        f32x4 a = acc[mi][ni];
        uint2 u;
        u.x = (unsigned)f2bf(a[0]) | ((unsigned)f2bf(a[1]) << 16);
        u.y = (unsigned)f2bf(a[2]) | ((unsigned)f2bf(a[3]) << 16);
        *(uint2*)(Xbuf + (size_t)p * CCH + o) = u;
      }
  } else {
    // D[p][o]: p = pblk+mi*16+lg*4+r, o = w*64+ni*16+lr. f32 NCHW + bias.
#pragma unroll
    for (int ni = 0; ni < 4; ni++) {
      int o = w * 64 + ni * 16 + lr;
      float bv = bias[o];
#pragma unroll
      for (int mi = 0; mi < 4; mi++) {
        int p = pblk + mi * 16 + lg * 4;
        f32x4 a = acc[mi][ni];
        float4 st = {a[0] + bv, a[1] + bv, a[2] + bv, a[3] + bv};
        *(float4*)(outY + ((size_t)z * CCH + o) * PP + p) = st;
      }
    }
  }
}

// ---------------------------------------------------------------------------
// Attention, LDS-staged, bf16 in/out (f32 LDS + math). Same structure as R3.
// ---------------------------------------------------------------------------
#define TX 32
#define TY 8
#define HX 34
#define HY 10
#define NHALO (HX * HY)
#define NSLOT (NHALO * 8)

__global__ __launch_bounds__(256)
void attn_lds(const u16* __restrict__ Kt, const u16* __restrict__ Vt,
              u16* __restrict__ Qt, const float* __restrict__ pe_dw,
              const float* __restrict__ pe_pw) {
  __shared__ float kv[NHALO * 32];     // 43,520 B
  __shared__ float coef[81];
  const int t = threadIdx.x;
  if (t < 81) coef[t] = pe_pw[t] * pe_dw[t % 9];

  const int x0 = blockIdx.x * TX;
  const int y0 = blockIdx.y * TY;
  const int b = blockIdx.z >> 3;
  const int h = blockIdx.z & 7;
  const size_t nbase = (size_t)b * PP * CCH + h * CH;

  const int lx = t & 31;
  const int ly = t >> 5;
  const int p = (y0 + ly) * WW + (x0 + lx);
  const size_t pixbase = nbase + (size_t)p * CCH;

  // ---- stage K halo (zero-fill OOB) ----
  for (int s = t; s < NSLOT; s += 256) {
    int pix = s >> 3, j = s & 7;
    int hy = pix / HX, hx = pix - hy * HX;
    int gx = x0 - 1 + hx, gy = y0 - 1 + hy;
    float4 v = make_float4(0.f, 0.f, 0.f, 0.f);
    if (gx >= 0 && gx < WW && gy >= 0 && gy < HH)
      v = unpack8(*(const uint2*)(Kt + nbase + (size_t)(gy * WW + gx) * CCH + j * 4));
    *(float4*)(&kv[pix * 32 + ((j ^ (hx & 7)) << 2)]) = v;
  }

  float4 q[8];
#pragma unroll
  for (int i = 0; i < 4; i++) {
    uint4 u = *(const uint4*)(Qt + pixbase + i * 8);
    q[2 * i] = unpack8(make_uint2(u.x, u.y));
    q[2 * i + 1] = unpack8(make_uint2(u.z, u.w));
  }
  __syncthreads();

  // ---- scores ----
  float f[9];
#pragma unroll
  for (int kk = 0; kk < 9; kk++) {
    int hx = lx + kk % 3, hy = ly + kk / 3;
    const float* kp = &kv[(hy * HX + hx) * 32];
    int sw = hx & 7;
    float s = 0.f;
#pragma unroll
    for (int j = 0; j < 8; j++) {
      float4 kvv = *(const float4*)(kp + ((j ^ sw) << 2));
      s = fmaf(q[j].x, kvv.x, s);
      s = fmaf(q[j].y, kvv.y, s);
      s = fmaf(q[j].z, kvv.z, s);
      s = fmaf(q[j].w, kvv.w, s);
    }
    f[kk] = s;
  }

  // ---- PE mix + softmax over 9 ----
  float g[9], m = -1e30f;
#pragma unroll
  for (int k2 = 0; k2 < 9; k2++) {
    float s = 0.f;
#pragma unroll
    for (int kk = 0; kk < 9; kk++) s = fmaf(coef[k2 * 9 + kk], f[kk], s);
    g[k2] = s;
    m = fmaxf(m, s);
  }
  float ssum = 0.f;
#pragma unroll
  for (int k2 = 0; k2 < 9; k2++) {
    g[k2] = __expf(g[k2] - m);
    ssum += g[k2];
  }
  float inv = 1.f / ssum;
#pragma unroll
  for (int k2 = 0; k2 < 9; k2++) g[k2] *= inv;

  // ---- stage V halo ----
  __syncthreads();
  for (int s = t; s < NSLOT; s += 256) {
    int pix = s >> 3, j = s & 7;
    int hy = pix / HX, hx = pix - hy * HX;
    int gx = x0 - 1 + hx, gy = y0 - 1 + hy;
    float4 v = make_float4(0.f, 0.f, 0.f, 0.f);
    if (gx >= 0 && gx < WW && gy >= 0 && gy < HH)
      v = unpack8(*(const uint2*)(Vt + nbase + (size_t)(gy * WW + gx) * CCH + j * 4));
    *(float4*)(&kv[pix * 32 + ((j ^ (hx & 7)) << 2)]) = v;
  }
  __syncthreads();

  // ---- O = sum_k g[k] * V[neighbor k] ----
  float4 o[8];
#pragma unroll
  for (int j = 0; j < 8; j++) o[j] = make_float4(0.f, 0.f, 0.f, 0.f);
#pragma unroll
  for (int kk = 0; kk < 9; kk++) {
    int hx = lx + kk % 3, hy = ly + kk / 3;
    const float* vp = &kv[(hy * HX + hx) * 32];
    int sw = hx & 7;
    float gv = g[kk];
#pragma unroll
    for (int j = 0; j < 8; j++) {
      float4 vv = *(const float4*)(vp + ((j ^ sw) << 2));
      o[j].x = fmaf(gv, vv.x, o[j].x);
      o[j].y = fmaf(gv, vv.y, o[j].y);
      o[j].z = fmaf(gv, vv.z, o[j].z);
      o[j].w = fmaf(gv, vv.w, o[j].w);
    }
  }
#pragma unroll
  for (int i = 0; i < 4; i++) {
    uint4 st;
    st.x = (unsigned)f2bf(o[2 * i].x) | ((unsigned)f2bf(o[2 * i].y) << 16);
    st.y = (unsigned)f2bf(o[2 * i].z) | ((unsigned)f2bf(o[2 * i].w) << 16);
    st.z = (unsigned)f2bf(o[2 * i + 1].x) | ((unsigned)f2bf(o[2 * i + 1].y) << 16);
    st.w = (unsigned)f2bf(o[2 * i + 1].z) | ((unsigned)f2bf(o[2 * i + 1].w) << 16);
    *(uint4*)(Qt + pixbase + i * 8) = st;
  }
}

// ---------------------------------------------------------------------------
extern "C" void kernel_launch(void* const* d_in, const int* in_sizes, int n_in,
                              void* d_out, int out_size, void* d_ws, size_t ws_size,
                              hipStream_t stream) {
  const float* q     = (const float*)d_in[0];
  const float* k     = (const float*)d_in[1];
  const float* v     = (const float*)d_in[2];
  const float* wq    = (const float*)d_in[3];
  const float* pe_dw = (const float*)d_in[4];
  const float* pe_pw = (const float*)d_in[5];
  const float* wo    = (const float*)d_in[6];
  const float* bo    = (const float*)d_in[7];
  float* out = (float*)d_out;

  const size_t seg = (size_t)BB * PP * CCH;      // elements per [B,P,C] tensor
  u16* Xcl = (u16*)d_ws;                         // 3*seg bf16: q,k,v (in-place proj)
  u16* Wbf = Xcl + 3 * seg;                      // 131072 bf16: wq | wo

  wcvt<<<128, 256, 0, stream>>>(wq, wo, Wbf);
  prepass<<<dim3(PP / 64, CCH / 32, 12), 256, 0, stream>>>(q, k, v, Xcl);

  // Q/K/V projection, in-place over Xcl segments (z = which*4 + b)
  gemm_mfma<0><<<dim3(PP / 64, 1, 12), 256, 0, stream>>>(Xcl, Wbf, nullptr, nullptr);

  u16* Qs = Xcl;
  u16* Ks = Xcl + seg;
  u16* Vs = Xcl + 2 * seg;
  attn_lds<<<dim3(WW / TX, HH / TY, BB * 8), 256, 0, stream>>>(Ks, Vs, Qs, pe_dw, pe_pw);

  // out projection: reads O (in Q segment), writes f32 NCHW + bias
  gemm_mfma<1><<<dim3(PP / 64, 1, BB), 256, 0, stream>>>(Qs, Wbf + 65536, bo, out);
}